// Round 8
// baseline (715.318 us; speedup 1.0000x reference)
//
#include <hip/hip_runtime.h>
#include <stdint.h>

typedef unsigned int u32;
typedef unsigned short u16;

using s16x8 = __attribute__((ext_vector_type(8))) short;
using f32x4 = __attribute__((ext_vector_type(4))) float;

#define N_NODES_C 50000
#define N_EDGES_C 800000
#define N_GRAPHS_C 256
#define N_FEAT_C 128
#define N_HID_C 256

static __device__ __forceinline__ float bf2f(u16 u) {
  union { u32 u; float f; } c; c.u = ((u32)u) << 16; return c.f;
}
static __device__ __forceinline__ u16 f2bf(float f) {
  union { float f; u32 u; } c; c.f = f;
  u32 u = c.u;
  return (u16)((u + 0x7fffu + ((u >> 16) & 1u)) >> 16);
}

static __device__ __forceinline__ void gload_lds16(const u16* g, u16* l) {
  __builtin_amdgcn_global_load_lds(
      (const __attribute__((address_space(1))) unsigned int*)g,
      (__attribute__((address_space(3))) unsigned int*)l, 16, 0, 0);
}

// ---------- weight transpose + workspace zeroing ----------
__global__ void convt_all_kernel(const float* __restrict__ Wa, const float* __restrict__ Wb,
                                 const float* __restrict__ Wc, const float* __restrict__ Wd,
                                 const float* __restrict__ We, const float* __restrict__ Wf,
                                 u16* oa, u16* ob, u16* oc, u16* od, u16* oe, u16* of_,
                                 int* cnt, int* flags, int* donecnt,
                                 float* stats0, float* stats1, float* xpool) {
  int m = blockIdx.y;
  if (m == 6) {  // zero pass
    int idx = blockIdx.x * 256 + threadIdx.x;   // 65536 threads
    if (idx <= N_NODES_C) cnt[idx] = 0;
    if (idx < 64) flags[idx] = 0;
    if (idx < 2) donecnt[idx] = 0;
    if (idx < 512) { stats0[idx] = 0.f; stats1[idx] = 0.f; }
    if (idx < N_GRAPHS_C * N_HID_C) xpool[idx] = 0.f;
    return;
  }
  const float* W; u16* o; int K;
  switch (m) {
    case 0: W = Wa; o = oa; K = 128; break;
    case 1: W = Wb; o = ob; K = 256; break;
    case 2: W = Wc; o = oc; K = 256; break;
    case 3: W = Wd; o = od; K = 256; break;
    case 4: W = We; o = oe; K = 256; break;
    default: W = Wf; o = of_; K = 256; break;
  }
  int idx = blockIdx.x * 256 + threadIdx.x;
  if (idx >= K * 256) return;
  int n = idx / K, k = idx - n * K;
  o[idx] = f2bf(W[(size_t)k * 256 + n]);  // o[n][k] = W[k][n]
}

// slice 0: f32->bf16 convert of x; slice 1: degree count
__global__ void cvt_count_kernel(const float* __restrict__ x, u16* __restrict__ xb, int n4,
                                 const int* __restrict__ dst, int* __restrict__ cnt, int E) {
  int idx = blockIdx.x * 256 + threadIdx.x;
  if (blockIdx.y == 0) {
    if (idx >= n4) return;
    float4 v = reinterpret_cast<const float4*>(x)[idx];
    u32 lo = (u32)f2bf(v.x) | ((u32)f2bf(v.y) << 16);
    u32 hi = (u32)f2bf(v.z) | ((u32)f2bf(v.w) << 16);
    uint2 w; w.x = lo; w.y = hi;
    reinterpret_cast<uint2*>(xb)[idx] = w;
  } else {
    if (idx < E) atomicAdd(&cnt[dst[idx]], 1);
  }
}

// single-kernel scan via decoupled lookback (49 resident blocks) [R6-verified]
__global__ void scan_fused_kernel(const int* __restrict__ cnt, int* __restrict__ offs,
                                  int* __restrict__ cursor, int* __restrict__ flags, int n) {
  __shared__ int sd[1024];
  __shared__ int prefix_sh;
  int b = blockIdx.x;
  int i = b * 1024 + (int)threadIdx.x;
  int v = (i < n) ? cnt[i] : 0;
  sd[threadIdx.x] = v;
  __syncthreads();
  for (int off = 1; off < 1024; off <<= 1) {
    int t = ((int)threadIdx.x >= off) ? sd[threadIdx.x - off] : 0;
    __syncthreads();
    sd[threadIdx.x] += t;
    __syncthreads();
  }
  if (threadIdx.x == 0) {
    int total = sd[1023];
    atomicExch(&flags[b], (total << 1) | 1);   // publish (sum,flag) packed
    int p = 0;
    for (int j = 0; j < b; j++) {
      int f;
      do { f = atomicAdd(&flags[j], 0); } while (!(f & 1));
      p += (f >> 1);
    }
    prefix_sh = p;
  }
  __syncthreads();
  int excl = sd[threadIdx.x] - v + prefix_sh;
  if (i < n) { offs[i] = excl; cursor[i] = excl; }
  if (i == n) offs[n] = N_EDGES_C;
}

__global__ void fill_kernel(const int* __restrict__ src, const int* __restrict__ dst,
                            int* __restrict__ cursor, int* __restrict__ csr, int E) {
  int e = blockIdx.x * 256 + threadIdx.x;
  if (e < E) {
    int p = atomicAdd(&cursor[dst[e]], 1);
    csr[p] = src[e];
  }
}

// ---------- aggregation ----------
// AFFINE=false: out_i = x_i + sum_j x_j
// AFFINE=true:  inputs are pre-BN h; out_i = sc*(h_i + sum_j h_j) + (1+deg_i)*bi
//               also writes concat_prev row = sc*h_i + bi (f32)
template <int D, bool AFFINE>
__global__ __launch_bounds__(256) void agg_kernel(const u16* __restrict__ xin,
                                                  const int* __restrict__ offs,
                                                  const int* __restrict__ csr,
                                                  const float* __restrict__ sb,
                                                  float* __restrict__ concat_prev,
                                                  u16* __restrict__ hout) {
  constexpr int LPE = D / 8;       // lanes per edge (16 or 32)
  constexpr int EPW = 64 / LPE;    // edge slots per wave (4 or 2)
  int wid = threadIdx.x >> 6, lane = threadIdx.x & 63;
  int node = blockIdx.x * 4 + wid;
  if (node >= N_NODES_C) return;
  int sub = lane / LPE;
  int fl = lane % LPE;
  int f0 = fl * 8;
  float acc[8], own[8];
  if (sub == 0) {
    uint4 v = *reinterpret_cast<const uint4*>(xin + (size_t)node * D + f0);
    const u32* pv = reinterpret_cast<const u32*>(&v);
#pragma unroll
    for (int t = 0; t < 4; t++) {
      acc[2 * t] = bf2f((u16)pv[t]);
      acc[2 * t + 1] = bf2f((u16)(pv[t] >> 16));
      own[2 * t] = acc[2 * t];
      own[2 * t + 1] = acc[2 * t + 1];
    }
  } else {
#pragma unroll
    for (int t = 0; t < 8; t++) acc[t] = 0.f;
  }
  int e0 = offs[node];
  int e1 = offs[node + 1];
  int e = e0 + sub;
  if (EPW == 2) {
    for (; e + 3 * EPW < e1; e += 4 * EPW) {
      int s0 = csr[e], s1 = csr[e + EPW], s2 = csr[e + 2 * EPW], s3 = csr[e + 3 * EPW];
      uint4 v0 = *reinterpret_cast<const uint4*>(xin + (size_t)s0 * D + f0);
      uint4 v1 = *reinterpret_cast<const uint4*>(xin + (size_t)s1 * D + f0);
      uint4 v2 = *reinterpret_cast<const uint4*>(xin + (size_t)s2 * D + f0);
      uint4 v3 = *reinterpret_cast<const uint4*>(xin + (size_t)s3 * D + f0);
      const u32* p0 = reinterpret_cast<const u32*>(&v0);
      const u32* p1 = reinterpret_cast<const u32*>(&v1);
      const u32* p2 = reinterpret_cast<const u32*>(&v2);
      const u32* p3 = reinterpret_cast<const u32*>(&v3);
#pragma unroll
      for (int t = 0; t < 4; t++) {
        acc[2 * t] += (bf2f((u16)p0[t]) + bf2f((u16)p1[t])) +
                      (bf2f((u16)p2[t]) + bf2f((u16)p3[t]));
        acc[2 * t + 1] += (bf2f((u16)(p0[t] >> 16)) + bf2f((u16)(p1[t] >> 16))) +
                          (bf2f((u16)(p2[t] >> 16)) + bf2f((u16)(p3[t] >> 16)));
      }
    }
  } else {
    for (; e + EPW < e1; e += 2 * EPW) {
      int s0 = csr[e], s1 = csr[e + EPW];
      uint4 v0 = *reinterpret_cast<const uint4*>(xin + (size_t)s0 * D + f0);
      uint4 v1 = *reinterpret_cast<const uint4*>(xin + (size_t)s1 * D + f0);
      const u32* p0 = reinterpret_cast<const u32*>(&v0);
      const u32* p1 = reinterpret_cast<const u32*>(&v1);
#pragma unroll
      for (int t = 0; t < 4; t++) {
        acc[2 * t] += bf2f((u16)p0[t]) + bf2f((u16)p1[t]);
        acc[2 * t + 1] += bf2f((u16)(p0[t] >> 16)) + bf2f((u16)(p1[t] >> 16));
      }
    }
  }
  for (; e < e1; e += EPW) {
    int s = csr[e];
    uint4 v = *reinterpret_cast<const uint4*>(xin + (size_t)s * D + f0);
    const u32* pv = reinterpret_cast<const u32*>(&v);
#pragma unroll
    for (int t = 0; t < 4; t++) {
      acc[2 * t] += bf2f((u16)pv[t]);
      acc[2 * t + 1] += bf2f((u16)(pv[t] >> 16));
    }
  }
#pragma unroll
  for (int j = 0; j < 8; j++) {
    if (EPW == 4) acc[j] += __shfl_xor(acc[j], 16, 64);
    acc[j] += __shfl_xor(acc[j], 32, 64);
  }
  if (sub == 0) {
    if (AFFINE) {
      float4 sca = *reinterpret_cast<const float4*>(sb + f0);
      float4 scb = *reinterpret_cast<const float4*>(sb + f0 + 4);
      float4 bia = *reinterpret_cast<const float4*>(sb + 256 + f0);
      float4 bib = *reinterpret_cast<const float4*>(sb + 256 + f0 + 4);
      float sc[8] = {sca.x, sca.y, sca.z, sca.w, scb.x, scb.y, scb.z, scb.w};
      float bi[8] = {bia.x, bia.y, bia.z, bia.w, bib.x, bib.y, bib.z, bib.w};
      // concat row = BN(own)
      float4 y0, y1;
      y0.x = fmaf(own[0], sc[0], bi[0]); y0.y = fmaf(own[1], sc[1], bi[1]);
      y0.z = fmaf(own[2], sc[2], bi[2]); y0.w = fmaf(own[3], sc[3], bi[3]);
      y1.x = fmaf(own[4], sc[4], bi[4]); y1.y = fmaf(own[5], sc[5], bi[5]);
      y1.z = fmaf(own[6], sc[6], bi[6]); y1.w = fmaf(own[7], sc[7], bi[7]);
      *reinterpret_cast<float4*>(concat_prev + (size_t)node * 768 + f0) = y0;
      *reinterpret_cast<float4*>(concat_prev + (size_t)node * 768 + f0 + 4) = y1;
      float dp1 = (float)(e1 - e0 + 1);
#pragma unroll
      for (int j = 0; j < 8; j++) acc[j] = fmaf(acc[j], sc[j], bi[j] * dp1);
    }
    u32 w[4];
#pragma unroll
    for (int t = 0; t < 4; t++)
      w[t] = (u32)f2bf(acc[2 * t]) | ((u32)f2bf(acc[2 * t + 1]) << 16);
    *reinterpret_cast<uint4*>(hout + (size_t)node * D + f0) =
        *reinterpret_cast<const uint4*>(w);
  }
}

// ---------- bf16 MFMA GEMM: C[M,256] = A[M,K] @ B[K,256]; Bt[256][K] ----------
// R3 config: 512 threads, 8 waves; BM=128, BN=256 (full width), BK=64.
// STATS: accumulate BN stats + last-block computes sb. POOL: atomic global_add_pool.
template <int K, bool RELU, bool OUTF32, bool STATS, bool POOL>
__global__ __launch_bounds__(512, 2) void gemm_kernel(
    const u16* __restrict__ A, const u16* __restrict__ Bt,
    u16* __restrict__ outB, float* __restrict__ outF, int ldc,
    float* __restrict__ statsp, const float* __restrict__ gamma,
    const float* __restrict__ beta, float* __restrict__ sbout,
    int* __restrict__ donecnt, const int* __restrict__ batch,
    float* __restrict__ xpool) {
  constexpr int BM = 128, BK = 64;
  __shared__ u16 Al[BM * BK];    // 16 KB, linear rows of 128B, XOR-swizzled contents
  __shared__ u16 Bl[256 * BK];   // 32 KB
  __shared__ int amlast;
  const int tid = threadIdx.x;
  const int wid = tid >> 6, lane = tid & 63;
  const int brow = blockIdx.x * BM;
  const int wr = (wid >> 2) * 64;   // 0 / 64
  const int wc = (wid & 3) * 64;    // 0 / 64 / 128 / 192
  f32x4 acc[4][4] = {};

  const int lrow = lane >> 3;            // row within 8-row chunk
  const int lw = lane & 7;               // 16B slot within 128B row
  const int colA = (lw ^ lrow) * 8;      // pre-swizzled global column (u16 units)
  const int sw = (lane & 7) << 3;        // read-side XOR

  for (int k0 = 0; k0 < K; k0 += BK) {
#pragma unroll
    for (int i = 0; i < 6; i++) {
      int c = wid * 6 + i;               // 48 chunks of 1KB: 16 for A, 32 for B
      if (c < 16) {
        int r = c * 8 + lrow;
        int gr = brow + r;
        gr = gr < N_NODES_C ? gr : N_NODES_C - 1;
        gload_lds16(A + (size_t)gr * K + k0 + colA, &Al[c * 512]);
      } else {
        int cc = c - 16;
        int r = cc * 8 + lrow;           // row of Bt = output column
        gload_lds16(Bt + (size_t)r * K + k0 + colA, &Bl[cc * 512]);
      }
    }
    __syncthreads();
#pragma unroll
    for (int ks = 0; ks < BK; ks += 32) {
      const int kk = ks + (lane >> 4) * 8;
      const int ki = kk ^ sw;
      s16x8 a[4], b[4];
#pragma unroll
      for (int m = 0; m < 4; m++)
        a[m] = *reinterpret_cast<const s16x8*>(&Al[(wr + m * 16 + (lane & 15)) * 64 + ki]);
#pragma unroll
      for (int n = 0; n < 4; n++)
        b[n] = *reinterpret_cast<const s16x8*>(&Bl[(wc + n * 16 + (lane & 15)) * 64 + ki]);
#pragma unroll
      for (int m = 0; m < 4; m++)
#pragma unroll
        for (int n = 0; n < 4; n++)
          acc[m][n] = __builtin_amdgcn_mfma_f32_16x16x32_bf16(a[m], b[n], acc[m][n], 0, 0, 0);
    }
    __syncthreads();
  }

  const int cb = wc + (lane & 15);
  const int rsub = (lane >> 4) * 4;
  float s1[4] = {0.f, 0.f, 0.f, 0.f}, s2[4] = {0.f, 0.f, 0.f, 0.f};
#pragma unroll
  for (int m = 0; m < 4; m++) {
#pragma unroll
    for (int r = 0; r < 4; r++) {
      int row = brow + wr + m * 16 + rsub + r;
      if (row >= N_NODES_C) continue;
      int bg = 0;
      if (POOL) bg = batch[row];
#pragma unroll
      for (int n = 0; n < 4; n++) {
        float v = acc[m][n][r];
        if (RELU) v = v > 0.f ? v : 0.f;
        int col = cb + n * 16;
        if (OUTF32)
          outF[(size_t)row * ldc + col] = v;
        else
          outB[(size_t)row * ldc + col] = f2bf(v);
        if (STATS) { s1[n] += v; s2[n] += v * v; }
        if (POOL) atomicAdd(&xpool[(size_t)bg * 256 + col], v);
      }
    }
  }
  if (STATS) {
#pragma unroll
    for (int n = 0; n < 4; n++) {
      float a0 = s1[n], b0 = s2[n];
      a0 += __shfl_xor(a0, 16, 64);
      b0 += __shfl_xor(b0, 16, 64);
      a0 += __shfl_xor(a0, 32, 64);
      b0 += __shfl_xor(b0, 32, 64);
      if (lane < 16) {
        atomicAdd(&statsp[cb + n * 16], a0);
        atomicAdd(&statsp[256 + cb + n * 16], b0);
      }
    }
    __threadfence();
    if (tid == 0) amlast = (atomicAdd(donecnt, 1) == (int)gridDim.x - 1) ? 1 : 0;
    __syncthreads();
    if (amlast && tid < 256) {  // last block computes BN scale/bias [R6-verified]
      int f = tid;
      const float invM = 1.0f / (float)N_NODES_C;
      float s = atomicAdd(&statsp[f], 0.0f);
      float sq = atomicAdd(&statsp[256 + f], 0.0f);
      float mean = s * invM;
      float var = sq * invM - mean * mean;
      float sc = gamma[f] * rsqrtf(var + 1e-5f);
      sbout[f] = sc;
      sbout[256 + f] = beta[f] - mean * sc;
    }
  }
}

extern "C" void kernel_launch(void* const* d_in, const int* in_sizes, int n_in,
                              void* d_out, int out_size, void* d_ws, size_t ws_size,
                              hipStream_t stream) {
  (void)in_sizes; (void)n_in; (void)out_size; (void)ws_size;
  const float* x = (const float*)d_in[0];
  const int* ei = (const int*)d_in[1];
  const int* batch = (const int*)d_in[2];
  const float* W1_0 = (const float*)d_in[3];
  const float* W2_0 = (const float*)d_in[4];
  const float* gamma0 = (const float*)d_in[5];
  const float* beta0 = (const float*)d_in[6];
  const float* W1_1 = (const float*)d_in[7];
  const float* W2_1 = (const float*)d_in[8];
  const float* gamma1 = (const float*)d_in[9];
  const float* beta1 = (const float*)d_in[10];
  const float* W1_2 = (const float*)d_in[11];
  const float* W2_2 = (const float*)d_in[12];

  float* out = (float*)d_out;
  float* xpool = out;                                  // [256,256]
  float* concat = out + (size_t)N_GRAPHS_C * N_HID_C;  // [50000,768]

  char* ws = (char*)d_ws;
  size_t off = 0;
  auto alloc = [&](size_t bytes) -> char* {
    char* p = ws + off;
    off = (off + bytes + 255) & ~(size_t)255;
    return p;
  };
  int* cnt = (int*)alloc((N_NODES_C + 1) * 4);
  int* offs = (int*)alloc((N_NODES_C + 1) * 4);
  int* cursor = (int*)alloc(N_NODES_C * 4);
  int* flags = (int*)alloc(64 * 4);
  int* donecnt = (int*)alloc(2 * 4);
  int* csr = (int*)alloc((size_t)N_EDGES_C * 4);
  u16* xb = (u16*)alloc((size_t)N_NODES_C * N_FEAT_C * 2);
  u16* hin = (u16*)alloc((size_t)N_NODES_C * N_HID_C * 2);   // agg out
  u16* tbuf = (u16*)alloc((size_t)N_NODES_C * N_HID_C * 2);  // gemm1 out
  u16* hpre = (u16*)alloc((size_t)N_NODES_C * N_HID_C * 2);  // gemm2 out (pre-BN)
  u16* w10t = (u16*)alloc((size_t)N_FEAT_C * N_HID_C * 2);
  u16* w20t = (u16*)alloc((size_t)N_HID_C * N_HID_C * 2);
  u16* w11t = (u16*)alloc((size_t)N_HID_C * N_HID_C * 2);
  u16* w21t = (u16*)alloc((size_t)N_HID_C * N_HID_C * 2);
  u16* w12t = (u16*)alloc((size_t)N_HID_C * N_HID_C * 2);
  u16* w22t = (u16*)alloc((size_t)N_HID_C * N_HID_C * 2);
  float* stats0 = (float*)alloc(512 * 4);
  float* stats1 = (float*)alloc(512 * 4);
  float* sb0 = (float*)alloc(512 * 4);
  float* sb1 = (float*)alloc(512 * 4);

  const int* srcv = ei;
  const int* dstv = ei + N_EDGES_C;
  const int nb = (N_NODES_C + 1023) / 1024;   // 49
  const int ggrid = (N_NODES_C + 127) / 128;  // 391
  const int n4 = N_NODES_C * N_FEAT_C / 4;    // 1.6M

  convt_all_kernel<<<dim3(256, 7), 256, 0, stream>>>(
      W1_0, W2_0, W1_1, W2_1, W1_2, W2_2, w10t, w20t, w11t, w21t, w12t, w22t,
      cnt, flags, donecnt, stats0, stats1, xpool);
  cvt_count_kernel<<<dim3((n4 + 255) / 256, 2), 256, 0, stream>>>(
      x, xb, n4, dstv, cnt, N_EDGES_C);

  scan_fused_kernel<<<nb, 1024, 0, stream>>>(cnt, offs, cursor, flags, N_NODES_C);
  fill_kernel<<<(N_EDGES_C + 255) / 256, 256, 0, stream>>>(srcv, dstv, cursor, csr, N_EDGES_C);

  // ---- Layer 0 ----
  agg_kernel<128, false><<<(N_NODES_C + 3) / 4, 256, 0, stream>>>(
      xb, offs, csr, nullptr, nullptr, hin);
  gemm_kernel<128, true, false, false, false><<<ggrid, 512, 0, stream>>>(
      hin, w10t, tbuf, nullptr, N_HID_C, nullptr, nullptr, nullptr, nullptr, nullptr,
      nullptr, nullptr);
  gemm_kernel<256, true, false, true, false><<<ggrid, 512, 0, stream>>>(
      tbuf, w20t, hpre, nullptr, N_HID_C, stats0, gamma0, beta0, sb0, donecnt,
      nullptr, nullptr);

  // ---- Layer 1 (agg applies BN0 affine; writes concat[:,0:256] f32) ----
  agg_kernel<256, true><<<(N_NODES_C + 3) / 4, 256, 0, stream>>>(
      hpre, offs, csr, sb0, concat + 0, hin);
  gemm_kernel<256, true, false, false, false><<<ggrid, 512, 0, stream>>>(
      hin, w11t, tbuf, nullptr, N_HID_C, nullptr, nullptr, nullptr, nullptr, nullptr,
      nullptr, nullptr);
  gemm_kernel<256, true, false, true, false><<<ggrid, 512, 0, stream>>>(
      tbuf, w21t, hpre, nullptr, N_HID_C, stats1, gamma1, beta1, sb1, donecnt + 1,
      nullptr, nullptr);

  // ---- Layer 2 (agg applies BN1 affine; writes concat[:,256:512] f32) ----
  agg_kernel<256, true><<<(N_NODES_C + 3) / 4, 256, 0, stream>>>(
      hpre, offs, csr, sb1, concat + 256, hin);
  gemm_kernel<256, true, false, false, false><<<ggrid, 512, 0, stream>>>(
      hin, w12t, tbuf, nullptr, N_HID_C, nullptr, nullptr, nullptr, nullptr, nullptr,
      nullptr, nullptr);
  gemm_kernel<256, false, true, false, true><<<ggrid, 512, 0, stream>>>(
      tbuf, w22t, nullptr, concat + 512, 768, nullptr, nullptr, nullptr, nullptr, nullptr,
      batch, xpool);
}

// Round 9
// 445.198 us; speedup vs baseline: 1.6067x; 1.6067x over previous
//
#include <hip/hip_runtime.h>
#include <stdint.h>

typedef unsigned int u32;
typedef unsigned short u16;

using s16x8 = __attribute__((ext_vector_type(8))) short;
using f32x4 = __attribute__((ext_vector_type(4))) float;

#define N_NODES_C 50000
#define N_EDGES_C 800000
#define N_GRAPHS_C 256
#define N_FEAT_C 128
#define N_HID_C 256

static __device__ __forceinline__ float bf2f(u16 u) {
  union { u32 u; float f; } c; c.u = ((u32)u) << 16; return c.f;
}
static __device__ __forceinline__ u16 f2bf(float f) {
  union { float f; u32 u; } c; c.f = f;
  u32 u = c.u;
  return (u16)((u + 0x7fffu + ((u >> 16) & 1u)) >> 16);
}

static __device__ __forceinline__ void gload_lds16(const u16* g, u16* l) {
  __builtin_amdgcn_global_load_lds(
      (const __attribute__((address_space(1))) unsigned int*)g,
      (__attribute__((address_space(3))) unsigned int*)l, 16, 0, 0);
}

// ---------- weight transpose + workspace zeroing ----------
__global__ void convt_all_kernel(const float* __restrict__ Wa, const float* __restrict__ Wb,
                                 const float* __restrict__ Wc, const float* __restrict__ Wd,
                                 const float* __restrict__ We, const float* __restrict__ Wf,
                                 u16* oa, u16* ob, u16* oc, u16* od, u16* oe, u16* of_,
                                 int* cnt, int* flags, float* stats0, float* stats1) {
  int m = blockIdx.y;
  if (m == 6) {  // zero pass
    int idx = blockIdx.x * 256 + threadIdx.x;
    if (idx <= N_NODES_C) cnt[idx] = 0;
    if (idx < 64) flags[idx] = 0;
    if (idx < 512) { stats0[idx] = 0.f; stats1[idx] = 0.f; }
    return;
  }
  const float* W; u16* o; int K;
  switch (m) {
    case 0: W = Wa; o = oa; K = 128; break;
    case 1: W = Wb; o = ob; K = 256; break;
    case 2: W = Wc; o = oc; K = 256; break;
    case 3: W = Wd; o = od; K = 256; break;
    case 4: W = We; o = oe; K = 256; break;
    default: W = Wf; o = of_; K = 256; break;
  }
  int idx = blockIdx.x * 256 + threadIdx.x;
  if (idx >= K * 256) return;
  int n = idx / K, k = idx - n * K;
  o[idx] = f2bf(W[(size_t)k * 256 + n]);  // o[n][k] = W[k][n]
}

// slice 0: f32->bf16 convert of x; slice 1: degree count
__global__ void cvt_count_kernel(const float* __restrict__ x, u16* __restrict__ xb, int n4,
                                 const int* __restrict__ dst, int* __restrict__ cnt, int E) {
  int idx = blockIdx.x * 256 + threadIdx.x;
  if (blockIdx.y == 0) {
    if (idx >= n4) return;
    float4 v = reinterpret_cast<const float4*>(x)[idx];
    u32 lo = (u32)f2bf(v.x) | ((u32)f2bf(v.y) << 16);
    u32 hi = (u32)f2bf(v.z) | ((u32)f2bf(v.w) << 16);
    uint2 w; w.x = lo; w.y = hi;
    reinterpret_cast<uint2*>(xb)[idx] = w;
  } else {
    if (idx < E) atomicAdd(&cnt[dst[idx]], 1);
  }
}

// single-kernel scan via decoupled lookback (49 resident blocks) [R6-verified]
__global__ void scan_fused_kernel(const int* __restrict__ cnt, int* __restrict__ offs,
                                  int* __restrict__ cursor, int* __restrict__ flags, int n) {
  __shared__ int sd[1024];
  __shared__ int prefix_sh;
  int b = blockIdx.x;
  int i = b * 1024 + (int)threadIdx.x;
  int v = (i < n) ? cnt[i] : 0;
  sd[threadIdx.x] = v;
  __syncthreads();
  for (int off = 1; off < 1024; off <<= 1) {
    int t = ((int)threadIdx.x >= off) ? sd[threadIdx.x - off] : 0;
    __syncthreads();
    sd[threadIdx.x] += t;
    __syncthreads();
  }
  if (threadIdx.x == 0) {
    int total = sd[1023];
    atomicExch(&flags[b], (total << 1) | 1);   // publish (sum,flag) packed
    int p = 0;
    for (int j = 0; j < b; j++) {
      int f;
      do { f = atomicAdd(&flags[j], 0); } while (!(f & 1));
      p += (f >> 1);
    }
    prefix_sh = p;
  }
  __syncthreads();
  int excl = sd[threadIdx.x] - v + prefix_sh;
  if (i < n) { offs[i] = excl; cursor[i] = excl; }
  if (i == n) offs[n] = N_EDGES_C;
}

__global__ void fill_kernel(const int* __restrict__ src, const int* __restrict__ dst,
                            int* __restrict__ cursor, int* __restrict__ csr, int E) {
  int e = blockIdx.x * 256 + threadIdx.x;
  if (e < E) {
    int p = atomicAdd(&cursor[dst[e]], 1);
    csr[p] = src[e];
  }
}

// ---------- aggregation (feature-split: each block handles 128 of LD feats) ----------
// AFFINE=false: out_i = x_i + sum_j x_j
// AFFINE=true:  inputs are pre-BN h; out_i = sc*(h_i + sum_j h_j) + (1+deg_i)*bi
//               also writes concat_prev row slice = sc*h_i + bi (f32)
template <int LD, bool AFFINE>
__global__ __launch_bounds__(256) void agg_kernel(const u16* __restrict__ xin,
                                                  const int* __restrict__ offs,
                                                  const int* __restrict__ csr,
                                                  const float* __restrict__ sb,
                                                  float* __restrict__ concat_prev,
                                                  u16* __restrict__ hout) {
  // 16 lanes per edge-slot, 4 slots per wave; 128 features per block
  int wid = threadIdx.x >> 6, lane = threadIdx.x & 63;
  int node = blockIdx.x * 4 + wid;
  if (node >= N_NODES_C) return;
  const int foff = (LD == 256) ? (int)blockIdx.y * 128 : 0;
  int sub = lane >> 4;        // 0..3
  int fl = lane & 15;         // 0..15
  int f0 = foff + fl * 8;
  float acc[8], own[8];
  if (sub == 0) {
    uint4 v = *reinterpret_cast<const uint4*>(xin + (size_t)node * LD + f0);
    const u32* pv = reinterpret_cast<const u32*>(&v);
#pragma unroll
    for (int t = 0; t < 4; t++) {
      acc[2 * t] = bf2f((u16)pv[t]);
      acc[2 * t + 1] = bf2f((u16)(pv[t] >> 16));
      own[2 * t] = acc[2 * t];
      own[2 * t + 1] = acc[2 * t + 1];
    }
  } else {
#pragma unroll
    for (int t = 0; t < 8; t++) acc[t] = 0.f;
  }
  int e0 = offs[node];
  int e1 = offs[node + 1];
  int e = e0 + sub;
  for (; e + 4 < e1; e += 8) {   // 2 edges in flight per slot
    int s0 = csr[e], s1 = csr[e + 4];
    uint4 v0 = *reinterpret_cast<const uint4*>(xin + (size_t)s0 * LD + f0);
    uint4 v1 = *reinterpret_cast<const uint4*>(xin + (size_t)s1 * LD + f0);
    const u32* p0 = reinterpret_cast<const u32*>(&v0);
    const u32* p1 = reinterpret_cast<const u32*>(&v1);
#pragma unroll
    for (int t = 0; t < 4; t++) {
      acc[2 * t] += bf2f((u16)p0[t]) + bf2f((u16)p1[t]);
      acc[2 * t + 1] += bf2f((u16)(p0[t] >> 16)) + bf2f((u16)(p1[t] >> 16));
    }
  }
  for (; e < e1; e += 4) {
    int s = csr[e];
    uint4 v = *reinterpret_cast<const uint4*>(xin + (size_t)s * LD + f0);
    const u32* pv = reinterpret_cast<const u32*>(&v);
#pragma unroll
    for (int t = 0; t < 4; t++) {
      acc[2 * t] += bf2f((u16)pv[t]);
      acc[2 * t + 1] += bf2f((u16)(pv[t] >> 16));
    }
  }
#pragma unroll
  for (int j = 0; j < 8; j++) {
    acc[j] += __shfl_xor(acc[j], 16, 64);
    acc[j] += __shfl_xor(acc[j], 32, 64);
  }
  if (sub == 0) {
    if (AFFINE) {
      float4 sca = *reinterpret_cast<const float4*>(sb + f0);
      float4 scb = *reinterpret_cast<const float4*>(sb + f0 + 4);
      float4 bia = *reinterpret_cast<const float4*>(sb + 256 + f0);
      float4 bib = *reinterpret_cast<const float4*>(sb + 256 + f0 + 4);
      float sc[8] = {sca.x, sca.y, sca.z, sca.w, scb.x, scb.y, scb.z, scb.w};
      float bi[8] = {bia.x, bia.y, bia.z, bia.w, bib.x, bib.y, bib.z, bib.w};
      // concat row slice = BN(own)
      float4 y0, y1;
      y0.x = fmaf(own[0], sc[0], bi[0]); y0.y = fmaf(own[1], sc[1], bi[1]);
      y0.z = fmaf(own[2], sc[2], bi[2]); y0.w = fmaf(own[3], sc[3], bi[3]);
      y1.x = fmaf(own[4], sc[4], bi[4]); y1.y = fmaf(own[5], sc[5], bi[5]);
      y1.z = fmaf(own[6], sc[6], bi[6]); y1.w = fmaf(own[7], sc[7], bi[7]);
      *reinterpret_cast<float4*>(concat_prev + (size_t)node * 768 + f0) = y0;
      *reinterpret_cast<float4*>(concat_prev + (size_t)node * 768 + f0 + 4) = y1;
      float dp1 = (float)(e1 - e0 + 1);
#pragma unroll
      for (int j = 0; j < 8; j++) acc[j] = fmaf(acc[j], sc[j], bi[j] * dp1);
    }
    u32 w[4];
#pragma unroll
    for (int t = 0; t < 4; t++)
      w[t] = (u32)f2bf(acc[2 * t]) | ((u32)f2bf(acc[2 * t + 1]) << 16);
    *reinterpret_cast<uint4*>(hout + (size_t)node * LD + f0) =
        *reinterpret_cast<const uint4*>(w);
  }
}

// ---------- bf16 MFMA GEMM: C[M,256] = A[M,K] @ B[K,256]; Bt[256][K] ----------
// R3/R7 config: 512 threads, 8 waves; BM=128, BN=256 (full width), BK=64.
template <int K, bool RELU, bool OUTF32, bool STATS>
__global__ __launch_bounds__(512, 2) void gemm_kernel(const u16* __restrict__ A,
                                                      const u16* __restrict__ Bt,
                                                      u16* __restrict__ outB,
                                                      float* __restrict__ outF, int ldc,
                                                      float* __restrict__ statsp) {
  constexpr int BM = 128, BK = 64;
  __shared__ u16 Al[BM * BK];    // 16 KB, linear rows of 128B, XOR-swizzled contents
  __shared__ u16 Bl[256 * BK];   // 32 KB
  const int tid = threadIdx.x;
  const int wid = tid >> 6, lane = tid & 63;
  const int brow = blockIdx.x * BM;
  const int wr = (wid >> 2) * 64;   // 0 / 64
  const int wc = (wid & 3) * 64;    // 0 / 64 / 128 / 192
  f32x4 acc[4][4] = {};

  const int lrow = lane >> 3;            // row within 8-row chunk
  const int lw = lane & 7;               // 16B slot within 128B row
  const int colA = (lw ^ lrow) * 8;      // pre-swizzled global column (u16 units)
  const int sw = (lane & 7) << 3;        // read-side XOR

  for (int k0 = 0; k0 < K; k0 += BK) {
#pragma unroll
    for (int i = 0; i < 6; i++) {
      int c = wid * 6 + i;               // 48 chunks of 1KB: 16 for A, 32 for B
      if (c < 16) {
        int r = c * 8 + lrow;
        int gr = brow + r;
        gr = gr < N_NODES_C ? gr : N_NODES_C - 1;
        gload_lds16(A + (size_t)gr * K + k0 + colA, &Al[c * 512]);
      } else {
        int cc = c - 16;
        int r = cc * 8 + lrow;           // row of Bt = output column
        gload_lds16(Bt + (size_t)r * K + k0 + colA, &Bl[cc * 512]);
      }
    }
    __syncthreads();
#pragma unroll
    for (int ks = 0; ks < BK; ks += 32) {
      const int kk = ks + (lane >> 4) * 8;
      const int ki = kk ^ sw;
      s16x8 a[4], b[4];
#pragma unroll
      for (int m = 0; m < 4; m++)
        a[m] = *reinterpret_cast<const s16x8*>(&Al[(wr + m * 16 + (lane & 15)) * 64 + ki]);
#pragma unroll
      for (int n = 0; n < 4; n++)
        b[n] = *reinterpret_cast<const s16x8*>(&Bl[(wc + n * 16 + (lane & 15)) * 64 + ki]);
#pragma unroll
      for (int m = 0; m < 4; m++)
#pragma unroll
        for (int n = 0; n < 4; n++)
          acc[m][n] = __builtin_amdgcn_mfma_f32_16x16x32_bf16(a[m], b[n], acc[m][n], 0, 0, 0);
    }
    __syncthreads();
  }

  const int cb = wc + (lane & 15);
  const int rsub = (lane >> 4) * 4;
  float s1[4] = {0.f, 0.f, 0.f, 0.f}, s2[4] = {0.f, 0.f, 0.f, 0.f};
#pragma unroll
  for (int m = 0; m < 4; m++) {
#pragma unroll
    for (int r = 0; r < 4; r++) {
      int row = brow + wr + m * 16 + rsub + r;
      if (row >= N_NODES_C) continue;
#pragma unroll
      for (int n = 0; n < 4; n++) {
        float v = acc[m][n][r];
        if (RELU) v = v > 0.f ? v : 0.f;
        int col = cb + n * 16;
        if (OUTF32)
          outF[(size_t)row * ldc + col] = v;
        else
          outB[(size_t)row * ldc + col] = f2bf(v);
        if (STATS) { s1[n] += v; s2[n] += v * v; }
      }
    }
  }
  if (STATS) {
#pragma unroll
    for (int n = 0; n < 4; n++) {
      float a0 = s1[n], b0 = s2[n];
      a0 += __shfl_xor(a0, 16, 64);
      b0 += __shfl_xor(b0, 16, 64);
      a0 += __shfl_xor(a0, 32, 64);
      b0 += __shfl_xor(b0, 32, 64);
      if (lane < 16) {
        atomicAdd(&statsp[cb + n * 16], a0);
        atomicAdd(&statsp[256 + cb + n * 16], b0);
      }
    }
  }
}

// ---------- BN scale/bias from stats ----------
__global__ void scalebias_kernel(const float* __restrict__ stats, const float* __restrict__ gamma,
                                 const float* __restrict__ beta, float* __restrict__ sb) {
  int f = threadIdx.x;
  const float invM = 1.0f / (float)N_NODES_C;
  float mean = stats[f] * invM;
  float var = stats[256 + f] * invM - mean * mean;
  float sc = gamma[f] * rsqrtf(var + 1e-5f);
  sb[f] = sc;
  sb[256 + f] = beta[f] - mean * sc;
}

// ---------- global_add_pool (batch sorted -> per-graph segments) ----------
__global__ __launch_bounds__(256) void pool_kernel(const float* __restrict__ c, int ldc,
                                                   const int* __restrict__ batch,
                                                   float* __restrict__ outp) {
  __shared__ float red[1024];
  int g = blockIdx.x;
  int wid = threadIdx.x >> 6, lane = threadIdx.x & 63;
  int lo = 0, hi = N_NODES_C;
  while (lo < hi) { int mid = (lo + hi) >> 1; if (batch[mid] < g) lo = mid + 1; else hi = mid; }
  int start = lo;
  hi = N_NODES_C;
  while (lo < hi) { int mid = (lo + hi) >> 1; if (batch[mid] <= g) lo = mid + 1; else hi = mid; }
  int end = lo;
  float acc[4] = {0.f, 0.f, 0.f, 0.f};
  for (int r = start + wid; r < end; r += 4) {
    float4 v = *reinterpret_cast<const float4*>(c + (size_t)r * ldc + lane * 4);
    acc[0] += v.x; acc[1] += v.y; acc[2] += v.z; acc[3] += v.w;
  }
#pragma unroll
  for (int j = 0; j < 4; j++) red[wid * 256 + lane * 4 + j] = acc[j];
  __syncthreads();
  int f = threadIdx.x;
  float s = red[f] + red[256 + f] + red[512 + f] + red[768 + f];
  outp[(size_t)g * 256 + f] = s;
}

extern "C" void kernel_launch(void* const* d_in, const int* in_sizes, int n_in,
                              void* d_out, int out_size, void* d_ws, size_t ws_size,
                              hipStream_t stream) {
  (void)in_sizes; (void)n_in; (void)out_size; (void)ws_size;
  const float* x = (const float*)d_in[0];
  const int* ei = (const int*)d_in[1];
  const int* batch = (const int*)d_in[2];
  const float* W1_0 = (const float*)d_in[3];
  const float* W2_0 = (const float*)d_in[4];
  const float* gamma0 = (const float*)d_in[5];
  const float* beta0 = (const float*)d_in[6];
  const float* W1_1 = (const float*)d_in[7];
  const float* W2_1 = (const float*)d_in[8];
  const float* gamma1 = (const float*)d_in[9];
  const float* beta1 = (const float*)d_in[10];
  const float* W1_2 = (const float*)d_in[11];
  const float* W2_2 = (const float*)d_in[12];

  float* out = (float*)d_out;
  float* xpool = out;                                  // [256,256]
  float* concat = out + (size_t)N_GRAPHS_C * N_HID_C;  // [50000,768]

  char* ws = (char*)d_ws;
  size_t off = 0;
  auto alloc = [&](size_t bytes) -> char* {
    char* p = ws + off;
    off = (off + bytes + 255) & ~(size_t)255;
    return p;
  };
  int* cnt = (int*)alloc((N_NODES_C + 1) * 4);
  int* offs = (int*)alloc((N_NODES_C + 1) * 4);
  int* cursor = (int*)alloc(N_NODES_C * 4);
  int* flags = (int*)alloc(64 * 4);
  int* csr = (int*)alloc((size_t)N_EDGES_C * 4);
  u16* xb = (u16*)alloc((size_t)N_NODES_C * N_FEAT_C * 2);
  u16* hin = (u16*)alloc((size_t)N_NODES_C * N_HID_C * 2);   // agg out
  u16* tbuf = (u16*)alloc((size_t)N_NODES_C * N_HID_C * 2);  // gemm1 out
  u16* hpre = (u16*)alloc((size_t)N_NODES_C * N_HID_C * 2);  // gemm2 out (pre-BN)
  u16* w10t = (u16*)alloc((size_t)N_FEAT_C * N_HID_C * 2);
  u16* w20t = (u16*)alloc((size_t)N_HID_C * N_HID_C * 2);
  u16* w11t = (u16*)alloc((size_t)N_HID_C * N_HID_C * 2);
  u16* w21t = (u16*)alloc((size_t)N_HID_C * N_HID_C * 2);
  u16* w12t = (u16*)alloc((size_t)N_HID_C * N_HID_C * 2);
  u16* w22t = (u16*)alloc((size_t)N_HID_C * N_HID_C * 2);
  float* stats0 = (float*)alloc(512 * 4);
  float* stats1 = (float*)alloc(512 * 4);
  float* sb0 = (float*)alloc(512 * 4);
  float* sb1 = (float*)alloc(512 * 4);

  const int* srcv = ei;
  const int* dstv = ei + N_EDGES_C;
  const int nb = (N_NODES_C + 1023) / 1024;   // 49
  const int ggrid = (N_NODES_C + 127) / 128;  // 391
  const int n4 = N_NODES_C * N_FEAT_C / 4;    // 1.6M
  const dim3 agrid1((N_NODES_C + 3) / 4, 1);
  const dim3 agrid2((N_NODES_C + 3) / 4, 2);

  convt_all_kernel<<<dim3(256, 7), 256, 0, stream>>>(
      W1_0, W2_0, W1_1, W2_1, W1_2, W2_2, w10t, w20t, w11t, w21t, w12t, w22t,
      cnt, flags, stats0, stats1);
  cvt_count_kernel<<<dim3((n4 + 255) / 256, 2), 256, 0, stream>>>(
      x, xb, n4, dstv, cnt, N_EDGES_C);

  scan_fused_kernel<<<nb, 1024, 0, stream>>>(cnt, offs, cursor, flags, N_NODES_C);
  fill_kernel<<<(N_EDGES_C + 255) / 256, 256, 0, stream>>>(srcv, dstv, cursor, csr, N_EDGES_C);

  // ---- Layer 0 ----
  agg_kernel<128, false><<<agrid1, 256, 0, stream>>>(
      xb, offs, csr, nullptr, nullptr, hin);
  gemm_kernel<128, true, false, false><<<ggrid, 512, 0, stream>>>(
      hin, w10t, tbuf, nullptr, N_HID_C, nullptr);
  gemm_kernel<256, true, false, true><<<ggrid, 512, 0, stream>>>(
      tbuf, w20t, hpre, nullptr, N_HID_C, stats0);
  scalebias_kernel<<<1, 256, 0, stream>>>(stats0, gamma0, beta0, sb0);

  // ---- Layer 1 (agg applies BN0 affine; writes concat[:,0:256] f32) ----
  agg_kernel<256, true><<<agrid2, 256, 0, stream>>>(
      hpre, offs, csr, sb0, concat + 0, hin);
  gemm_kernel<256, true, false, false><<<ggrid, 512, 0, stream>>>(
      hin, w11t, tbuf, nullptr, N_HID_C, nullptr);
  gemm_kernel<256, true, false, true><<<ggrid, 512, 0, stream>>>(
      tbuf, w21t, hpre, nullptr, N_HID_C, stats1);
  scalebias_kernel<<<1, 256, 0, stream>>>(stats1, gamma1, beta1, sb1);

  // ---- Layer 2 (agg applies BN1 affine; writes concat[:,256:512] f32) ----
  agg_kernel<256, true><<<agrid2, 256, 0, stream>>>(
      hpre, offs, csr, sb1, concat + 256, hin);
  gemm_kernel<256, true, false, false><<<ggrid, 512, 0, stream>>>(
      hin, w12t, tbuf, nullptr, N_HID_C, nullptr);
  gemm_kernel<256, false, true, false><<<ggrid, 512, 0, stream>>>(
      tbuf, w22t, nullptr, concat + 512, 768, nullptr);

  // ---- pool ----
  pool_kernel<<<N_GRAPHS_C, 256, 0, stream>>>(concat + 512, 768, batch, xpool);
}